// Round 1
// baseline (225.117 us; speedup 1.0000x reference)
//
#include <hip/hip_runtime.h>

#define D 512
#define EPS 1e-8f

__global__ __launch_bounds__(256) void OrthogonalLoss_kernel(
    const float* __restrict__ t1, const float* __restrict__ t2,
    const int* __restrict__ labels, float* __restrict__ out,
    unsigned int* __restrict__ ws, int n, int nblocks)
{
    // ws layout: [0..2] label counts, [3] ticket, [4..6] cos values (float)
    unsigned int* counts = ws;
    unsigned int* ticket = ws + 3;
    float* cosv = (float*)(ws + 4);

    const int tid = threadIdx.x;
    const int gid = blockIdx.x * blockDim.x + tid;

    // ---- label counting: one int4 (4 labels) per thread ----
    int n0 = 0, n1 = 0, n2 = 0;
    const int4* lab4 = (const int4*)labels;
    if (gid * 4 < n) {
        int4 v = lab4[gid];
        n0 = (v.x == 0) + (v.y == 0) + (v.z == 0) + (v.w == 0);
        n1 = (v.x == 1) + (v.y == 1) + (v.z == 1) + (v.w == 1);
        n2 = (v.x == 2) + (v.y == 2) + (v.z == 2) + (v.w == 2);
    }

    #pragma unroll
    for (int off = 32; off >= 1; off >>= 1) {
        n0 += __shfl_down(n0, off);
        n1 += __shfl_down(n1, off);
        n2 += __shfl_down(n2, off);
    }
    if ((tid & 63) == 0) {
        atomicAdd(&counts[0], (unsigned)n0);
        atomicAdd(&counts[1], (unsigned)n1);
        atomicAdd(&counts[2], (unsigned)n2);
    }

    // ---- block 0: the 3 cosine similarities over rows 0..2 ----
    if (blockIdx.x == 0) {
        float dot[3] = {0.f, 0.f, 0.f};
        float na[3]  = {0.f, 0.f, 0.f};
        float nb[3]  = {0.f, 0.f, 0.f};
        for (int d = tid; d < D; d += 256) {
            #pragma unroll
            for (int l = 0; l < 3; ++l) {
                float a = t1[l * D + d];
                float b = t2[l * D + d];
                dot[l] += a * b;
                na[l]  += a * a;
                nb[l]  += b * b;
            }
        }
        #pragma unroll
        for (int off = 32; off >= 1; off >>= 1) {
            #pragma unroll
            for (int l = 0; l < 3; ++l) {
                dot[l] += __shfl_down(dot[l], off);
                na[l]  += __shfl_down(na[l], off);
                nb[l]  += __shfl_down(nb[l], off);
            }
        }
        __shared__ float red[4][9];
        const int wave = tid >> 6;
        if ((tid & 63) == 0) {
            #pragma unroll
            for (int l = 0; l < 3; ++l) {
                red[wave][l * 3 + 0] = dot[l];
                red[wave][l * 3 + 1] = na[l];
                red[wave][l * 3 + 2] = nb[l];
            }
        }
        __syncthreads();
        if (tid == 0) {
            #pragma unroll
            for (int l = 0; l < 3; ++l) {
                float dd = 0.f, aa = 0.f, bb = 0.f;
                #pragma unroll
                for (int w = 0; w < 4; ++w) {
                    dd += red[w][l * 3 + 0];
                    aa += red[w][l * 3 + 1];
                    bb += red[w][l * 3 + 2];
                }
                float c = dd / fmaxf(sqrtf(aa) * sqrtf(bb), EPS);
                atomicAdd(&cosv[l], c);   // ws zeroed -> this stores c
            }
        }
    }

    // ---- completion ticket; last-finishing block computes final loss ----
    __syncthreads();        // barrier drains vmcnt -> this block's atomics done
    __threadfence();
    if (tid == 0) {
        unsigned old = atomicAdd(ticket, 1u);
        if (old == (unsigned)(nblocks - 1)) {
            // everyone (including block 0) has completed their atomics
            float c0 = atomicAdd(&cosv[0], 0.0f);
            float c1 = atomicAdd(&cosv[1], 0.0f);
            float c2 = atomicAdd(&cosv[2], 0.0f);
            unsigned m0 = atomicAdd(&counts[0], 0u);
            unsigned m1 = atomicAdd(&counts[1], 0u);
            unsigned m2 = atomicAdd(&counts[2], 0u);
            float total = (float)m0 * (1.0f - c0)
                        + (float)m2 * (1.0f - c2)
                        + (float)m1 * fabsf(c1);
            out[0] = total / (float)n;
        }
    }
}

extern "C" void kernel_launch(void* const* d_in, const int* in_sizes, int n_in,
                              void* d_out, int out_size, void* d_ws, size_t ws_size,
                              hipStream_t stream) {
    const float* t1     = (const float*)d_in[0];
    const float* t2     = (const float*)d_in[1];
    const int*   labels = (const int*)d_in[2];
    float* out = (float*)d_out;

    const int n = in_sizes[2];               // 65536 labels == N rows
    const int nthreads = (n + 3) / 4;        // one int4 per thread
    const int nblocks = (nthreads + 255) / 256;

    hipMemsetAsync(d_ws, 0, 64, stream);     // zero counters/ticket/cos slots
    OrthogonalLoss_kernel<<<nblocks, 256, 0, stream>>>(
        t1, t2, labels, out, (unsigned int*)d_ws, n, nblocks);
}

// Round 3
// 218.959 us; speedup vs baseline: 1.0281x; 1.0281x over previous
//
#include <hip/hip_runtime.h>

#define EPS 1e-8f

// Single-block kernel: no workspace, no memset node, no cross-block traffic.
// Work = count labels (n0,n1; n2 = n-n0-n1) + 3 cosine similarities over
// rows 0..2 of t1/t2 (D=512). Total input touched: 256 KB labels + 12 KB.
__global__ __launch_bounds__(1024) void OrthogonalLoss_kernel(
    const float* __restrict__ t1, const float* __restrict__ t2,
    const int* __restrict__ labels, float* __restrict__ out, int n)
{
    const int tid  = threadIdx.x;
    const int wave = tid >> 6;

    __shared__ int   redc[16][2];  // per-wave label counts (16 waves)
    __shared__ float redf[8][9];   // per-wave cosine partials (first 8 waves)

    // ---- label counting: int4 loads, grid(=block)-stride ----
    int c0 = 0, c1 = 0;
    const int n4 = n >> 2;
    const int4* lab4 = (const int4*)labels;
    for (int i = tid; i < n4; i += 1024) {
        int4 v = lab4[i];
        c0 += (v.x == 0) + (v.y == 0) + (v.z == 0) + (v.w == 0);
        c1 += (v.x == 1) + (v.y == 1) + (v.z == 1) + (v.w == 1);
    }
    for (int i = (n4 << 2) + tid; i < n; i += 1024) {   // tail (n%4)
        int v = labels[i];
        c0 += (v == 0);
        c1 += (v == 1);
    }
    #pragma unroll
    for (int off = 32; off >= 1; off >>= 1) {
        c0 += __shfl_down(c0, off);
        c1 += __shfl_down(c1, off);
    }
    if ((tid & 63) == 0) { redc[wave][0] = c0; redc[wave][1] = c1; }

    // ---- cosine partials: threads 0..511, one dim each, rows 0..2 ----
    float vals[9];
    if (tid < 512) {
        float a0 = t1[tid], a1 = t1[512 + tid], a2 = t1[1024 + tid];
        float b0 = t2[tid], b1 = t2[512 + tid], b2 = t2[1024 + tid];
        vals[0] = a0 * b0; vals[1] = a0 * a0; vals[2] = b0 * b0;
        vals[3] = a1 * b1; vals[4] = a1 * a1; vals[5] = b1 * b1;
        vals[6] = a2 * b2; vals[7] = a2 * a2; vals[8] = b2 * b2;
    } else {
        #pragma unroll
        for (int j = 0; j < 9; ++j) vals[j] = 0.f;
    }
    #pragma unroll
    for (int off = 32; off >= 1; off >>= 1) {
        #pragma unroll
        for (int j = 0; j < 9; ++j) vals[j] += __shfl_down(vals[j], off);
    }
    if (tid < 512 && (tid & 63) == 0) {
        #pragma unroll
        for (int j = 0; j < 9; ++j) redf[wave][j] = vals[j];
    }

    __syncthreads();

    // ---- final: thread 0 folds 16 count-partials + 8 cosine-partials ----
    if (tid == 0) {
        int n0 = 0, n1 = 0;
        #pragma unroll
        for (int w = 0; w < 16; ++w) { n0 += redc[w][0]; n1 += redc[w][1]; }
        int n2 = n - n0 - n1;   // labels ∈ {0,1,2}

        float s[9];
        #pragma unroll
        for (int j = 0; j < 9; ++j) {
            float t = 0.f;
            #pragma unroll
            for (int w = 0; w < 8; ++w) t += redf[w][j];
            s[j] = t;
        }
        float cos0 = s[0] / fmaxf(sqrtf(s[1]) * sqrtf(s[2]), EPS);
        float cos1 = s[3] / fmaxf(sqrtf(s[4]) * sqrtf(s[5]), EPS);
        float cos2 = s[6] / fmaxf(sqrtf(s[7]) * sqrtf(s[8]), EPS);

        float total = (float)n0 * (1.0f - cos0)
                    + (float)n2 * (1.0f - cos2)
                    + (float)n1 * fabsf(cos1);
        out[0] = total / (float)n;
    }
}

extern "C" void kernel_launch(void* const* d_in, const int* in_sizes, int n_in,
                              void* d_out, int out_size, void* d_ws, size_t ws_size,
                              hipStream_t stream) {
    const float* t1     = (const float*)d_in[0];
    const float* t2     = (const float*)d_in[1];
    const int*   labels = (const int*)d_in[2];
    float* out = (float*)d_out;

    const int n = in_sizes[2];   // 65536 labels
    OrthogonalLoss_kernel<<<1, 1024, 0, stream>>>(t1, t2, labels, out, n);
}